// Round 4
// baseline (403.245 us; speedup 1.0000x reference)
//
#include <hip/hip_runtime.h>

#define N_NODES 100000
#define F_IN 128
#define F_HID 32
#define NXCD 8

__device__ __forceinline__ unsigned get_xcc() {
    unsigned x;
    asm volatile("s_getreg_b32 %0, hwreg(HW_REG_XCC_ID)" : "=s"(x));
    return x & (NXCD - 1);
}

// ---------------- degree histograms (XCD-private, L2-local atomics) ----------------

__global__ void hist_kernel(const int* __restrict__ src, const int* __restrict__ dst,
                            unsigned* __restrict__ histOut, unsigned* __restrict__ histIn, int E) {
    unsigned x = get_xcc();
    unsigned* ho = histOut + x * N_NODES;
    unsigned* hi = histIn + x * N_NODES;
    int e = blockIdx.x * blockDim.x + threadIdx.x;
    if (e < E) {
        // XCD-local atomic: executes at this XCD's TCC, no device write-through
        __hip_atomic_fetch_add(&ho[src[e]], 1u, __ATOMIC_RELAXED, __HIP_MEMORY_SCOPE_WORKGROUP);
        __hip_atomic_fetch_add(&hi[dst[e]], 1u, __ATOMIC_RELAXED, __HIP_MEMORY_SCOPE_WORKGROUP);
    }
}

__global__ void reduce_norm_kernel(const unsigned* __restrict__ histOut,
                                   const unsigned* __restrict__ histIn,
                                   int* __restrict__ deg_in, float* __restrict__ norm_out,
                                   float* __restrict__ norm_in, int n) {
    int i = blockIdx.x * blockDim.x + threadIdx.x;
    if (i >= n) return;
    unsigned si = 0, so = 0;
#pragma unroll
    for (int x = 0; x < NXCD; ++x) {
        si += histIn[x * N_NODES + i];
        so += histOut[x * N_NODES + i];
    }
    deg_in[i] = (int)si;
    norm_in[i] = rsqrtf((float)(si > 1u ? si : 1u));
    norm_out[i] = rsqrtf((float)(so > 1u ? so : 1u));
}

// ---------------- CSR build: scan + scatter ----------------

__global__ void scan_block_reduce(const int* __restrict__ deg, int* __restrict__ bsum, int n) {
    __shared__ int s[256];
    int i = blockIdx.x * 256 + threadIdx.x;
    s[threadIdx.x] = (i < n) ? deg[i] : 0;
    __syncthreads();
    for (int stride = 128; stride > 0; stride >>= 1) {
        if (threadIdx.x < stride) s[threadIdx.x] += s[threadIdx.x + stride];
        __syncthreads();
    }
    if (threadIdx.x == 0) bsum[blockIdx.x] = s[0];
}

// single block, 512 threads, nb <= 512
__global__ void scan_bsums(const int* __restrict__ bsum, int* __restrict__ bscan, int nb) {
    __shared__ int buf[2][512];
    int t = threadIdx.x;
    buf[0][t] = (t < nb) ? bsum[t] : 0;
    __syncthreads();
    int cur = 0;
    for (int off = 1; off < 512; off <<= 1) {
        int v = buf[cur][t];
        if (t >= off) v += buf[cur][t - off];
        buf[cur ^ 1][t] = v;
        cur ^= 1;
        __syncthreads();
    }
    if (t < nb) bscan[t] = (t == 0) ? 0 : buf[cur][t - 1];
}

__global__ void scan_final(const int* __restrict__ deg, const int* __restrict__ bscan,
                           int* __restrict__ row_ptr, int n) {
    __shared__ int buf[2][256];
    int t = threadIdx.x;
    int i = blockIdx.x * 256 + t;
    int v = (i < n) ? deg[i] : 0;
    buf[0][t] = v;
    __syncthreads();
    int cur = 0;
    for (int off = 1; off < 256; off <<= 1) {
        int x = buf[cur][t];
        if (t >= off) x += buf[cur][t - off];
        buf[cur ^ 1][t] = x;
        cur ^= 1;
        __syncthreads();
    }
    if (i < n) row_ptr[i] = bscan[blockIdx.x] + buf[cur][t] - v;  // exclusive
}

__global__ void scatter_kernel(const int* __restrict__ src, const int* __restrict__ dst,
                               const int* __restrict__ row_ptr, int* __restrict__ cnt,
                               int* __restrict__ col, int E) {
    int e = blockIdx.x * blockDim.x + threadIdx.x;
    if (e < E) {
        int d = dst[e];
        int pos = atomicAdd(&cnt[d], 1);  // must be device scope: placement is global
        col[row_ptr[d] + pos] = src[e];
    }
}

// ---------------- projection (layer 1) with norm_out prescale ----------------

__global__ void gemm1_kernel(const float* __restrict__ x, const float* __restrict__ W,
                             const float* __restrict__ norm_out, float* __restrict__ h, int n) {
    __shared__ float Wl[F_IN * F_HID];  // 16 KB
    for (int i = threadIdx.x; i < F_IN * F_HID; i += blockDim.x) Wl[i] = W[i];
    __syncthreads();
    int node = blockIdx.x * blockDim.x + threadIdx.x;
    if (node >= n) return;
    float acc[F_HID];
#pragma unroll
    for (int j = 0; j < F_HID; ++j) acc[j] = 0.f;
    const float4* row = reinterpret_cast<const float4*>(x + (size_t)node * F_IN);
#pragma unroll 2
    for (int k4 = 0; k4 < F_IN / 4; ++k4) {
        float4 v = row[k4];
        const float* w0 = &Wl[(k4 * 4 + 0) * F_HID];
        const float* w1 = &Wl[(k4 * 4 + 1) * F_HID];
        const float* w2 = &Wl[(k4 * 4 + 2) * F_HID];
        const float* w3 = &Wl[(k4 * 4 + 3) * F_HID];
#pragma unroll
        for (int j = 0; j < F_HID; ++j)
            acc[j] += v.x * w0[j] + v.y * w1[j] + v.z * w2[j] + v.w * w3[j];
    }
    float s = norm_out[node];
    float* out = h + (size_t)node * F_HID;
#pragma unroll
    for (int j = 0; j < F_HID; ++j) out[j] = acc[j] * s;
}

// ---------------- fused aggregation kernels ----------------

__global__ void agg1_kernel(const float* __restrict__ h1s, const int* __restrict__ row_ptr,
                            const int* __restrict__ deg_in, const int* __restrict__ col,
                            const float* __restrict__ norm_in, const float* __restrict__ norm_out,
                            const float* __restrict__ b1, const float* __restrict__ W2,
                            float* __restrict__ h2s, int n) {
    __shared__ float W2l[F_HID * F_HID];
    for (int i = threadIdx.x; i < F_HID * F_HID; i += blockDim.x) W2l[i] = W2[i];
    __syncthreads();
    int lane = threadIdx.x & 31;
    int node = blockIdx.x * (blockDim.x >> 5) + (threadIdx.x >> 5);
    if (node >= n) return;
    int start = row_ptr[node];
    int deg = deg_in[node];
    float acc0 = 0.f, acc1 = 0.f;
    int j = 0;
    for (; j + 1 < deg; j += 2) {
        int s0 = col[start + j];
        int s1 = col[start + j + 1];
        acc0 += h1s[(size_t)s0 * F_HID + lane];
        acc1 += h1s[(size_t)s1 * F_HID + lane];
    }
    if (j < deg) acc0 += h1s[(size_t)col[start + j] * F_HID + lane];
    float t = (acc0 + acc1) * norm_in[node] + b1[lane];
    t = t > 0.f ? t : 0.f;
    float o = 0.f;
#pragma unroll
    for (int k = 0; k < F_HID; ++k) {
        float tk = __shfl(t, k, 32);
        o += tk * W2l[k * F_HID + lane];
    }
    h2s[(size_t)node * F_HID + lane] = o * norm_out[node];
}

__global__ void agg2_kernel(const float* __restrict__ h2s, const int* __restrict__ row_ptr,
                            const int* __restrict__ deg_in, const int* __restrict__ col,
                            const float* __restrict__ norm_in, const float* __restrict__ b2,
                            float* __restrict__ out, int n) {
    int lane = threadIdx.x & 31;
    int node = blockIdx.x * (blockDim.x >> 5) + (threadIdx.x >> 5);
    if (node >= n) return;
    int start = row_ptr[node];
    int deg = deg_in[node];
    float acc0 = 0.f, acc1 = 0.f;
    int j = 0;
    for (; j + 1 < deg; j += 2) {
        int s0 = col[start + j];
        int s1 = col[start + j + 1];
        acc0 += h2s[(size_t)s0 * F_HID + lane];
        acc1 += h2s[(size_t)s1 * F_HID + lane];
    }
    if (j < deg) acc0 += h2s[(size_t)col[start + j] * F_HID + lane];
    out[(size_t)node * F_HID + lane] = (acc0 + acc1) * norm_in[node] + b2[lane];
}

// ---------------- launch ----------------

static inline size_t align256(size_t x) { return (x + 255) & ~(size_t)255; }

extern "C" void kernel_launch(void* const* d_in, const int* in_sizes, int n_in,
                              void* d_out, int out_size, void* d_ws, size_t ws_size,
                              hipStream_t stream) {
    const float* features = (const float*)d_in[0];
    const float* W1 = (const float*)d_in[1];
    const float* b1 = (const float*)d_in[2];
    const float* W2 = (const float*)d_in[3];
    const float* b2 = (const float*)d_in[4];
    const int* src = (const int*)d_in[5];
    const int* dst = (const int*)d_in[6];
    const int E = in_sizes[5];
    const int n = N_NODES;
    const int NB = (n + 255) / 256;  // 391 <= 512
    float* out = (float*)d_out;

    char* ws = (char*)d_ws;
    size_t off = 0;
    int* deg_in = (int*)(ws + off);       off += align256((size_t)n * 4);
    float* norm_out = (float*)(ws + off); off += align256((size_t)n * 4);
    float* norm_in = (float*)(ws + off);  off += align256((size_t)n * 4);
    int* row_ptr = (int*)(ws + off);      off += align256((size_t)n * 4);
    int* cnt = (int*)(ws + off);          off += align256((size_t)n * 4);
    int* bsum = (int*)(ws + off);         off += align256(512 * 4);
    int* bscan = (int*)(ws + off);        off += align256(512 * 4);

    // Overlapped region: histograms (phase 1) reuse the same bytes as h1s (phase 2).
    size_t histOff = off;
    unsigned* histIn = (unsigned*)(ws + histOff);                          // 8N u32 = 3.2 MB
    unsigned* histOut = (unsigned*)(ws + histOff + (size_t)NXCD * n * 4);  // 3.2 MB
    float* h1s = (float*)(ws + histOff);                                   // 12.8 MB (after hists die)
    float* h2s = (float*)(ws + histOff + (size_t)n * F_HID * 4);           // 12.8 MB
    int* col = (int*)(ws + histOff + (size_t)2 * n * F_HID * 4);           // 6.4 MB

    // zero histograms (both copies, contiguous) and scatter cursors
    (void)hipMemsetAsync(histIn, 0, (size_t)2 * NXCD * n * 4, stream);
    (void)hipMemsetAsync(cnt, 0, (size_t)n * 4, stream);

    // degrees via XCD-private histograms + reduce
    hist_kernel<<<(E + 255) / 256, 256, 0, stream>>>(src, dst, histOut, histIn, E);
    reduce_norm_kernel<<<NB, 256, 0, stream>>>(histOut, histIn, deg_in, norm_out, norm_in, n);

    // CSR over dst
    scan_block_reduce<<<NB, 256, 0, stream>>>(deg_in, bsum, n);
    scan_bsums<<<1, 512, 0, stream>>>(bsum, bscan, NB);
    scan_final<<<NB, 256, 0, stream>>>(deg_in, bscan, row_ptr, n);
    scatter_kernel<<<(E + 255) / 256, 256, 0, stream>>>(src, dst, row_ptr, cnt, col, E);

    // layer 1 projection (+ norm_out prescale)
    gemm1_kernel<<<NB, 256, 0, stream>>>(features, W1, norm_out, h1s, n);

    // layer-1 aggregate + relu/bias + GEMM2 + prescale
    agg1_kernel<<<(n + 7) / 8, 256, 0, stream>>>(h1s, row_ptr, deg_in, col, norm_in,
                                                 norm_out, b1, W2, h2s, n);
    // layer-2 aggregate + bias -> out
    agg2_kernel<<<(n + 7) / 8, 256, 0, stream>>>(h2s, row_ptr, deg_in, col, norm_in, b2, out, n);
}